// Round 1
// 234.199 us; speedup vs baseline: 1.0177x; 1.0177x over previous
//
#include <hip/hip_runtime.h>
#include <hip/hip_bf16.h>

// HoloAttention: out = (Re(cumsum_t(x@Wv^T * e^{i t f}) * e^{-i t f})) @ Wo^T
// (k-projection in reference is dead code — skipped.)
//
// R7: GEMMs rebuilt as 256x256-tile / BK=64 / 8-wave (2Mx4N) kernels with a
// counted-vmcnt software pipeline (T3+T4): raw s_barrier (no __syncthreads
// vmcnt(0) drain), prefetch distance 2 K-tiles, s_waitcnt vmcnt(8) in the
// main loop, setprio(1) around 16-MFMA clusters (T5). LDS 128 KiB, 2 slots,
// row-XOR swizzle (same scheme as R6, 0 bank conflicts). Grid = 256 blocks
// = 1/CU, XCD-swizzled. FUSE_SUMS epilogue re-derived for the 2x4 wave grid
// (each wave owns 2 t-chunks of 64 rows).
// Kernel chain: cast -> gemm1(+sums) -> pass2 -> pass3 -> gemm2.

#define B_  2
#define T_  8192
#define D_  1024
#define BT_ 16384
#define CS_ 64
#define NCHUNK_ 128

typedef __attribute__((ext_vector_type(4))) float f32x4;
typedef __attribute__((ext_vector_type(8))) short bf16x8;

static __device__ inline unsigned short f2bf(float f) {
    union { float f; unsigned int u; } a;
    a.f = f;
    unsigned int u = a.u;
    return (unsigned short)((u + 0x7FFFu + ((u >> 16) & 1u)) >> 16);  // RNE
}
static __device__ inline float bf2f(unsigned short h) {
    union { unsigned int u; float f; } a;
    a.u = ((unsigned int)h) << 16;
    return a.f;
}

// One fused cast: x (4194304 float4) | Wv (262144) | Wo (262144)
__global__ __launch_bounds__(256) void cast_all(const float* __restrict__ x,
                                                const float* __restrict__ Wv,
                                                const float* __restrict__ Wo,
                                                unsigned short* __restrict__ xb,
                                                unsigned short* __restrict__ wvb,
                                                unsigned short* __restrict__ wob) {
    const int nx = BT_ * D_ / 4;
    const int nw = D_ * D_ / 4;
    int i = blockIdx.x * 256 + threadIdx.x;
    const float4* src;
    unsigned short* dst;
    int j;
    if (i < nx)            { src = (const float4*)x;  dst = xb;  j = i; }
    else if (i < nx + nw)  { src = (const float4*)Wv; dst = wvb; j = i - nx; }
    else                   { src = (const float4*)Wo; dst = wob; j = i - nx - nw; }
    float4 v = src[j];
    ushort4 o;
    o.x = f2bf(v.x); o.y = f2bf(v.y); o.z = f2bf(v.z); o.w = f2bf(v.w);
    ((ushort4*)dst)[j] = o;
}

// C[M,N] = A[M,K] (bf16 row-major) @ Bm[N,K]^T (bf16 row-major).
// 256x256 tile, BK=64, 512 threads = 8 waves (wm = wave>>2 in {0,1} owns
// 128 rows; wn = wave&3 owns 64 cols). acc[8][4] f32x4 per thread.
// LDS: 2 slots x (A 256x64 + B 256x64) bf16 = 131072 B.
// Pipeline per iter t: vmcnt(8) -> barrier -> {ds_read + MFMA clusters}
// -> lgkmcnt(0) -> barrier -> issue K-tile t+2 into slot t&1.
// Safety: loads into a slot are only ISSUED after the barrier that all
// waves reach having drained lgkmcnt(0) for their reads of that slot.
template <bool BF16OUT, bool FUSE_SUMS>
__global__ __launch_bounds__(512, 2) void gemm_bt(const short* __restrict__ A,
                                                  const short* __restrict__ Bm,
                                                  void* __restrict__ Cout,
                                                  const float* __restrict__ freqs,
                                                  float* __restrict__ csum,
                                                  int M, int N, int K) {
    __shared__ short lds[65536];  // 2 x 32768 shorts (A at +0, B at +16384)
    const int tid = threadIdx.x;
    const int lane = tid & 63;
    const int wave = tid >> 6;
    const int wm = wave >> 2, wn = wave & 3;

    const int nb = N >> 8;               // N-blocks (4)
    const int id = blockIdx.x;
    const int xcd = id & 7;
    const int slot = id >> 3;
    const int bn = (slot % nb) * 256;
    const int bm = (xcd * ((M >> 8) >> 3) + slot / nb) * 256;

    // --- staging source pointers: 8 issues of 8 KB (512 thr x 16 B) each.
    // Issue c (0..3) covers rows c*64 + wave*8 + (lane>>3); column granule
    // is pre-swizzled so linear LDS dest == swizzled layout (rule #21).
    const int srow = lane >> 3;
    const int sg = lane & 7;
    const short* gsrc[8];
#pragma unroll
    for (int c = 0; c < 4; ++c) {
        const int r = c * 64 + wave * 8 + srow;
        const int col = (sg ^ (r & 7)) * 8;
        gsrc[c]     = A  + (size_t)(bm + r) * K + col;
        gsrc[c + 4] = Bm + (size_t)(bn + r) * K + col;
    }

    auto stage = [&](int kt, int sl) {
        const int koff = kt * 64;
        short* dstA = &lds[sl * 32768 + wave * 512];
        short* dstB = &lds[sl * 32768 + 16384 + wave * 512];
#pragma unroll
        for (int c = 0; c < 4; ++c) {
            __builtin_amdgcn_global_load_lds(
                (const __attribute__((address_space(1))) void*)(gsrc[c] + koff),
                (__attribute__((address_space(3))) void*)(dstA + c * 4096), 16, 0, 0);
            __builtin_amdgcn_global_load_lds(
                (const __attribute__((address_space(1))) void*)(gsrc[c + 4] + koff),
                (__attribute__((address_space(3))) void*)(dstB + c * 4096), 16, 0, 0);
        }
    };

    // --- fragment read offsets (shorts), swizzled to match staging.
    const int c4r = lane >> 4;
    int aoff[8][2], boff[4][2];
#pragma unroll
    for (int i = 0; i < 8; ++i) {
        const int m = wm * 128 + i * 16 + (lane & 15);
#pragma unroll
        for (int ks = 0; ks < 2; ++ks)
            aoff[i][ks] = m * 64 + (((ks * 4 + c4r) ^ (m & 7)) * 8);
    }
#pragma unroll
    for (int j = 0; j < 4; ++j) {
        const int n = wn * 64 + j * 16 + (lane & 15);
#pragma unroll
        for (int ks = 0; ks < 2; ++ks)
            boff[j][ks] = 16384 + n * 64 + (((ks * 4 + c4r) ^ (n & 7)) * 8);
    }

    f32x4 acc[8][4] = {};

    // --- prologue: K-tiles 0 and 1 in flight (16 loads/wave).
    stage(0, 0);
    stage(1, 1);

    const int NT = K >> 6;  // 16
#pragma unroll 1
    for (int t = 0; t < NT; ++t) {
        // my share of K-tile t landed (8 newest = K-tile t+1 may fly)
        if (t < NT - 1) asm volatile("s_waitcnt vmcnt(8)" ::: "memory");
        else            asm volatile("s_waitcnt vmcnt(0)" ::: "memory");
        __builtin_amdgcn_sched_barrier(0);
        __builtin_amdgcn_s_barrier();          // everyone's share landed
        __builtin_amdgcn_sched_barrier(0);

        const int sb = (t & 1) * 32768;
#pragma unroll
        for (int ks = 0; ks < 2; ++ks) {
            bf16x8 bb[4];
#pragma unroll
            for (int j = 0; j < 4; ++j)
                bb[j] = *(const bf16x8*)&lds[sb + boff[j][ks]];
#pragma unroll
            for (int ih = 0; ih < 2; ++ih) {
                bf16x8 aa[4];
#pragma unroll
                for (int ii = 0; ii < 4; ++ii)
                    aa[ii] = *(const bf16x8*)&lds[sb + aoff[ih * 4 + ii][ks]];
                __builtin_amdgcn_s_setprio(1);
#pragma unroll
                for (int ii = 0; ii < 4; ++ii)
#pragma unroll
                    for (int j = 0; j < 4; ++j)
                        acc[ih * 4 + ii][j] = __builtin_amdgcn_mfma_f32_16x16x32_bf16(
                            aa[ii], bb[j], acc[ih * 4 + ii][j], 0, 0, 0);
                __builtin_amdgcn_s_setprio(0);
            }
        }
        // all my LDS reads of slot t&1 complete before I pass the barrier
        asm volatile("s_waitcnt lgkmcnt(0)" ::: "memory");
        __builtin_amdgcn_sched_barrier(0);
        __builtin_amdgcn_s_barrier();          // slot t&1 free for rewrite
        __builtin_amdgcn_sched_barrier(0);
        if (t < NT - 2) stage(t + 2, t & 1);   // counted: awaited by vmcnt(8)
    }

    // --- epilogue: C write
    const int row0 = c4r * 4;
#pragma unroll
    for (int i = 0; i < 8; ++i) {
#pragma unroll
        for (int j = 0; j < 4; ++j) {
            const int col = bn + wn * 64 + j * 16 + (lane & 15);
#pragma unroll
            for (int r = 0; r < 4; ++r) {
                const size_t row = (size_t)bm + wm * 128 + i * 16 + row0 + r;
                if constexpr (BF16OUT)
                    ((unsigned short*)Cout)[row * N + col] = f2bf(acc[i][j][r]);
                else
                    ((float*)Cout)[row * N + col] = acc[i][j][r];
            }
        }
    }

    if constexpr (FUSE_SUMS) {
        // Wave (wm) covers t-chunks (trow>>6)+wm*2+ig for ig in {0,1}.
        const int b = bm >> 13;
        const int trow = bm & 8191;
#pragma unroll
        for (int ig = 0; ig < 2; ++ig) {
            const int chunk = (trow >> 6) + wm * 2 + ig;
            const int t0 = trow + wm * 128 + ig * 64 + c4r * 4;
#pragma unroll
            for (int j = 0; j < 4; ++j) {
                const int d = bn + wn * 64 + j * 16 + (lane & 15);
                const float f = freqs[d];
                float ss, cc2;
                sincosf((float)t0 * f, &ss, &cc2);
                float s1, c1;
                sincosf(f, &s1, &c1);
                // e13 = e1^13 via squarings (rows step +1 within r, +13 across i)
                float c2 = c1 * c1 - s1 * s1, s2 = 2.f * c1 * s1;
                float c4 = c2 * c2 - s2 * s2, s4 = 2.f * c2 * s2;
                float c8 = c4 * c4 - s4 * s4, s8 = 2.f * c4 * s4;
                float c12 = c8 * c4 - s8 * s4, s12 = s8 * c4 + c8 * s4;
                float c13 = c12 * c1 - s12 * s1, s13 = s12 * c1 + c12 * s1;
                float ar = 0.f, ai = 0.f;
                float cr = cc2, sr2 = ss;
#pragma unroll
                for (int ii = 0; ii < 4; ++ii) {
                    const int i = ig * 4 + ii;
#pragma unroll
                    for (int r = 0; r < 4; ++r) {
                        const float w = acc[i][j][r];
                        ar = fmaf(w, cr, ar); ai = fmaf(w, sr2, ai);
                        const float ec = (r < 3) ? c1 : c13;
                        const float es = (r < 3) ? s1 : s13;
                        const float nc = cr * ec - sr2 * es;
                        const float ns = sr2 * ec + cr * es;
                        cr = nc; sr2 = ns;
                    }
                }
                ar += __shfl_xor(ar, 16); ai += __shfl_xor(ai, 16);
                ar += __shfl_xor(ar, 32); ai += __shfl_xor(ai, 32);
                if (c4r == 0)
                    *(float2*)(csum + (((size_t)b * NCHUNK_ + chunk) * D_ + d) * 2) =
                        make_float2(ar, ai);
            }
        }
    }
}

// Pass 2: exclusive prefix of chunk sums per (b,d); 32-deep batches.
__global__ __launch_bounds__(256) void scan_pass2(float* __restrict__ csum) {
    const int g = blockIdx.x * 256 + threadIdx.x;  // 0 .. B*D-1
    const int b = g / D_;
    const int d = g % D_;
    float2* cs = (float2*)csum;
    const size_t base = (size_t)b * NCHUNK_ * D_ + d;
    float pr = 0.f, pi = 0.f;
    for (int cc = 0; cc < NCHUNK_; cc += 32) {
        float2 buf[32];
#pragma unroll
        for (int k = 0; k < 32; ++k) buf[k] = cs[base + (size_t)(cc + k) * D_];
#pragma unroll
        for (int k = 0; k < 32; ++k) {
            float r = buf[k].x, im = buf[k].y;
            buf[k] = make_float2(pr, pi);
            pr += r; pi += im;
        }
#pragma unroll
        for (int k = 0; k < 32; ++k) cs[base + (size_t)(cc + k) * D_] = buf[k];
    }
}

// Pass 3: replay chunk; retrieved = Re(mt * conj(rotor)) -> bf16; 2 d's/thread,
// CS=64, 8-row load batches, grid (NCHUNK, D/512, B) = 2048 waves.
__global__ __launch_bounds__(256) void scan_pass3(const unsigned short* __restrict__ v,
                                                  const float* __restrict__ freqs,
                                                  const float* __restrict__ csum,
                                                  unsigned short* __restrict__ ret) {
    const int chunk = blockIdx.x;
    const int d0 = blockIdx.y * 512 + threadIdx.x * 2;
    const int b = blockIdx.z;

    float fr[2], s[2], c[2], sf[2], cf[2], ar[2], ai[2];
    {
        float2 f2 = *(const float2*)(freqs + d0);
        fr[0] = f2.x; fr[1] = f2.y;
    }
    const float t0f = (float)(chunk * CS_);
#pragma unroll
    for (int k = 0; k < 2; ++k) {
        sincosf(t0f * fr[k], &s[k], &c[k]);
        sincosf(fr[k], &sf[k], &cf[k]);
    }
    {
        const float4 o = *(const float4*)(csum + (((size_t)b * NCHUNK_ + chunk) * D_ + d0) * 2);
        ar[0] = o.x; ai[0] = o.y; ar[1] = o.z; ai[1] = o.w;
    }
    const unsigned int* vp = (const unsigned int*)(v + ((size_t)b * T_ + chunk * CS_) * D_ + d0);
    unsigned int* rp = (unsigned int*)(ret + ((size_t)b * T_ + chunk * CS_) * D_ + d0);
    for (int tb = 0; tb < CS_; tb += 8) {
        unsigned int w[8];
#pragma unroll
        for (int u = 0; u < 8; ++u) w[u] = vp[(size_t)(tb + u) * (D_ / 2)];
#pragma unroll
        for (int u = 0; u < 8; ++u) {
            float wv[2], o[2];
            wv[0] = bf2f((unsigned short)w[u]);
            wv[1] = bf2f((unsigned short)(w[u] >> 16));
#pragma unroll
            for (int k = 0; k < 2; ++k) {
                ar[k] = fmaf(wv[k], c[k], ar[k]);
                ai[k] = fmaf(wv[k], s[k], ai[k]);
                o[k] = ar[k] * c[k] + ai[k] * s[k];   // Re(mt * (cos - i sin))
                float nc = c[k] * cf[k] - s[k] * sf[k];
                float ns = s[k] * cf[k] + c[k] * sf[k];
                c[k] = nc; s[k] = ns;
            }
            rp[(size_t)(tb + u) * (D_ / 2)] =
                (unsigned int)f2bf(o[0]) | ((unsigned int)f2bf(o[1]) << 16);
        }
    }
}

extern "C" void kernel_launch(void* const* d_in, const int* in_sizes, int n_in,
                              void* d_out, int out_size, void* d_ws, size_t ws_size,
                              hipStream_t stream) {
    const float* x     = (const float*)d_in[0];
    // d_in[1] = Wk (dead in reference)
    const float* Wv    = (const float*)d_in[2];
    const float* Wo    = (const float*)d_in[3];
    const float* freqs = (const float*)d_in[4];
    float* out = (float*)d_out;

    char* ws = (char*)d_ws;
    unsigned short* x_bf  = (unsigned short*)ws;                 // 33,554,432 B
    unsigned short* Wv_bf = (unsigned short*)(ws + 33554432);    //  2,097,152 B
    unsigned short* Wo_bf = (unsigned short*)(ws + 35651584);    //  2,097,152 B
    unsigned short* ret   = (unsigned short*)(ws + 37748736);    // 33,554,432 B
    float*          csum  = (float*)(ws + 71303168);             //  2,097,152 B (B*128*D*2*4)
    // v (bf16) lives in d_out's first half; dead before GEMM2 overwrites d_out.
    unsigned short* v_bf = (unsigned short*)d_out;

    // 1. fused casts (x | Wv | Wo)
    cast_all<<<(BT_ * D_ / 4 + 2 * D_ * D_ / 4) / 256, 256, 0, stream>>>(
        x, Wv, Wo, x_bf, Wv_bf, Wo_bf);

    // 2. v = x @ Wv^T (bf16 out) + fused per-chunk rotor sums
    gemm_bt<true, true><<<(BT_ / 256) * (D_ / 256), 512, 0, stream>>>(
        (const short*)x_bf, (const short*)Wv_bf, (void*)v_bf, freqs, csum, BT_, D_, D_);

    // 3. exclusive prefix over chunks, then replay+unbind
    scan_pass2<<<(B_ * D_) / 256, 256, 0, stream>>>(csum);
    dim3 p3grid(NCHUNK_, D_ / 512, B_);
    scan_pass3<<<p3grid, 256, 0, stream>>>(v_bf, freqs, csum, ret);

    // 4. out = retrieved @ Wo^T (fp32 out)
    gemm_bt<false, false><<<(BT_ / 256) * (D_ / 256), 512, 0, stream>>>(
        (const short*)ret, (const short*)Wo_bf, (void*)out, nullptr, nullptr, BT_, D_, D_);
}